// Round 12
// baseline (529.055 us; speedup 1.0000x reference)
//
#include <hip/hip_runtime.h>

// LSTM B=4096, T=512, I=2, H=50, O=3 — MFMA bf16x3, round 12.
// KEY CHANGE vs r10/r11: 2 INDEPENDENT blocks per CU to hide the per-t
// serial chain (barrier -> ds_read -> MFMA chain -> trans chain -> write ->
// barrier), which r10 proved intra-block waves cannot hide (occupancy 2x'd,
// wall unchanged). ROWS=8, 512 blocks x 8 waves (512 thr) -> 2 blocks/CU;
// the two blocks' barrier domains are independent and interleave.
// Wave owns 2 tiles (tau = 2*wvf + tt) sharing ONE set of B-frag reads.
//   A (M) = weight rows, m = 4*u_local + gate  (VGPR frags)
//   B (N) = h, n = batch row (cols 0..7 real, 8..15 pad) (4x ds_read_b128)
//   C: col=lane&15=batch, grp=lane>>4=unit-in-tile, reg=GATE
// K carries everything: k<50 h, k=50/51 x0/x1, k=52 bias (const 1.0).
// Waves 0..6 active (13 real tiles), wave 7 = x-writer. ONE barrier per t.

typedef short bf16x8 __attribute__((ext_vector_type(8)));
typedef float f32x4  __attribute__((ext_vector_type(4)));

#define T_STEPS 512
#define HID     50
#define ROWS    8                          // real batch rows per block
#define MROWS   16                         // tile N width (8 pad)
#define RSTRIDE 272                        // 17 x 16B granules per m-row
#define HBUF_SZ (MROWS * RSTRIDE)          // 4352 B
#define HF_OFF  (2 * HBUF_SZ)              // 8704 B
#define ARENA_SZ (HF_OFF + MROWS * 64 * 4) // 12800 B
#define NTHREADS 512

#define L2E  1.442695040888963f            // log2(e)
#define L2E2 2.885390081777927f            // 2*log2(e)

// (hi bf16 in low short, lo bf16 in high short), round-to-nearest both
__device__ __forceinline__ unsigned pack_hilo(float f) {
    unsigned u  = __float_as_uint(f);
    unsigned hi = (u + 0x7fffu + ((u >> 16) & 1u)) >> 16;
    float    fh = __uint_as_float(hi << 16);
    float    rl = f - fh;
    unsigned ul = __float_as_uint(rl);
    unsigned lo = (ul + 0x7fffu + ((ul >> 16) & 1u)) >> 16;
    return (hi & 0xFFFFu) | (lo << 16);
}

__global__ __launch_bounds__(NTHREADS, 4) void lstm_mfma8_kernel(
    const float* __restrict__ x,     // [B,T,2]
    const float* __restrict__ W_ih,  // [200,2]
    const float* __restrict__ W_hh,  // [200,50]
    const float* __restrict__ b_ih,  // [200]
    const float* __restrict__ b_hh,  // [200]
    const float* __restrict__ W_fc,  // [3,50]
    const float* __restrict__ b_fc,  // [3]
    float* __restrict__ out)         // [B,3]
{
    __shared__ __align__(16) char arena[ARENA_SZ];

    const int tid  = threadIdx.x;
    const int lane = tid & 63;
    const int wvf  = tid >> 6;         // wave 0..7
    const int col  = lane & 15;        // C col = batch row; A row index m
    const int grp  = lane >> 4;        // k-group; C row-group = unit-in-tile
    const int b0   = blockIdx.x * ROWS;

    // ---- zero arena ----
    for (int i = tid; i < ARENA_SZ / 4; i += NTHREADS) ((int*)arena)[i] = 0;

    // ---- A-frags (weights) in regs: tiles tau = 2*wvf + tt ----
    // A[m][k], lane provides m = col: unit u = tau*4 + (m>>2), gate g = m&3.
    bf16x8 awhi[2][2], awlo[2][2];   // [tt][kt]
    bool act[2];
#pragma unroll
    for (int tt = 0; tt < 2; ++tt) {
        const int tau = wvf * 2 + tt;
        act[tt] = (tau * 4) < HID;
        const int u = tau * 4 + (col >> 2);
        const int g = col & 3;
#pragma unroll
        for (int kt = 0; kt < 2; ++kt) {
            bf16x8 H, L;
#pragma unroll
            for (int e = 0; e < 8; ++e) {
                int k = kt * 32 + grp * 8 + e;
                float v = 0.f;
                if (act[tt] && u < HID) {
                    int j = g * HID + u;
                    if      (k < HID)  v = W_hh[j * HID + k];
                    else if (k == 50)  v = W_ih[2 * j + 0];
                    else if (k == 51)  v = W_ih[2 * j + 1];
                    else if (k == 52)  v = b_ih[j] + b_hh[j];
                }
                unsigned p = pack_hilo(v);
                H[e] = (short)(p & 0xFFFFu);
                L[e] = (short)(p >> 16);
            }
            awhi[tt][kt] = H;
            awlo[tt][kt] = L;
        }
    }

    __syncthreads();   // zeroing complete

    // const-1.0 at k=52 for REAL rows only (chunk 6, elems 4..5 b32),
    // both buffers; pad rows 8..15 and lo plane stay zero.
    if (tid < 2 * ROWS) {
        int buf = tid >> 3, m = tid & 7;
        *(unsigned*)(arena + buf * HBUF_SZ + m * RSTRIDE + 6 * 32 + 4 * 2) = 0x00003F80u;
    }
    // x writer: wave 7 (pad tiles), lanes 0..15 -> (m 0..7) x (comp 0..1)
    const int  xm = lane & 7;
    const int  xw = (lane >> 3) & 1;
    const bool xwriter = (wvf == 7) && (lane < 16);
    const float* xptr = x + (size_t)(b0 + xm) * (T_STEPS * 2) + xw;
    if (xwriter) {   // x(t=0) into buffer 0: k=50+xw -> chunk 6, elem 2+xw
        unsigned p = pack_hilo(xptr[0]);
        char* cell = arena + xm * RSTRIDE + 6 * 32 + (2 + xw) * 2;
        *(short*)cell        = (short)(p & 0xFFFFu);
        *(short*)(cell + 16) = (short)(p >> 16);
    }
    float xpre = xwriter ? xptr[1 * 2] : 0.f;   // prefetch x(t=1)

    float c2[2]   = {0.f, 0.f};    // cell state: my cell per tile
    float hreg[2] = {0.f, 0.f};

    __syncthreads();

    int pb = 0;
    for (int t = 0; t < T_STEPS; ++t) {
        char* db = arena + (pb ^ 1) * HBUF_SZ;

        if (act[0]) {
            // ---- B-frags (h/x/1.0): 4 raw ds_read_b128, col = batch ----
            const char* hb = arena + pb * HBUF_SZ + col * RSTRIDE;
            bf16x8 bh[2], bl[2];
#pragma unroll
            for (int kt = 0; kt < 2; ++kt) {
                const char* p = hb + (kt * 4 + grp) * 32;
                bh[kt] = *(const bf16x8*)p;
                bl[kt] = *(const bf16x8*)(p + 16);
            }

            // ---- per tile: 6 MFMA in two independent 3-chains ----
            f32x4 acc[2];
#pragma unroll
            for (int tt = 0; tt < 2; ++tt) {
                if (!act[tt]) continue;
                f32x4 a0 = {0.f, 0.f, 0.f, 0.f};
                f32x4 a1 = {0.f, 0.f, 0.f, 0.f};
                a0 = __builtin_amdgcn_mfma_f32_16x16x32_bf16(awhi[tt][0], bh[0], a0, 0, 0, 0);
                a1 = __builtin_amdgcn_mfma_f32_16x16x32_bf16(awhi[tt][1], bh[1], a1, 0, 0, 0);
                a0 = __builtin_amdgcn_mfma_f32_16x16x32_bf16(awlo[tt][0], bh[0], a0, 0, 0, 0);
                a1 = __builtin_amdgcn_mfma_f32_16x16x32_bf16(awlo[tt][1], bh[1], a1, 0, 0, 0);
                a0 = __builtin_amdgcn_mfma_f32_16x16x32_bf16(awhi[tt][0], bl[0], a0, 0, 0, 0);
                a1 = __builtin_amdgcn_mfma_f32_16x16x32_bf16(awhi[tt][1], bl[1], a1, 0, 0, 0);
                acc[tt] = a0 + a1;
            }

            // ---- epilogue: 1 cell per lane per active tile ----
#pragma unroll
            for (int tt = 0; tt < 2; ++tt) {
                if (!act[tt]) continue;
                const int u = (wvf * 2 + tt) * 4 + grp;   // my unit
                float pi = acc[tt][0], pf = acc[tt][1];
                float pg = acc[tt][2], po = acc[tt][3];
                float ei = __builtin_amdgcn_exp2f(-L2E  * pi);
                float ef = __builtin_amdgcn_exp2f(-L2E  * pf);
                float eg = __builtin_amdgcn_exp2f( L2E2 * pg);
                float eo = __builtin_amdgcn_exp2f(-L2E  * po);
                float sf    = __builtin_amdgcn_rcpf(1.0f + ef);
                float ig_tg = (eg - 1.0f) * __builtin_amdgcn_rcpf((1.0f + ei) * (eg + 1.0f));
                float c = sf * c2[tt] + ig_tg;
                c = fminf(fmaxf(c, -32.0f), 32.0f);       // keep exp2 finite
                c2[tt] = c;
                float ec = __builtin_amdgcn_exp2f(L2E2 * c);
                float h  = (ec - 1.0f) * __builtin_amdgcn_rcpf((1.0f + eo) * (ec + 1.0f));
                hreg[tt] = h;
                if (u < HID && col < ROWS) {              // mask pad units/rows
                    unsigned p = pack_hilo(h);
                    char* cell = db + col * RSTRIDE + (u >> 3) * 32 + (u & 7) * 2;
                    *(short*)cell        = (short)(p & 0xFFFFu);
                    *(short*)(cell + 16) = (short)(p >> 16);
                }
            }
        }

        // ---- x(t+1) into next buffer; prefetch x(t+2) ----
        if (xwriter) {
            unsigned p = pack_hilo(xpre);
            char* cell = db + xm * RSTRIDE + 6 * 32 + (2 + xw) * 2;
            *(short*)cell        = (short)(p & 0xFFFFu);
            *(short*)(cell + 16) = (short)(p >> 16);
            int t2 = (t + 2 < T_STEPS) ? t + 2 : T_STEPS - 1;
            xpre = xptr[(size_t)t2 * 2];
        }

        pb ^= 1;
        __syncthreads();
    }

    // ---- final FC: gather fp32 h, 24 threads compute out ----
    float* hf = (float*)(arena + HF_OFF);   // [16][64]
#pragma unroll
    for (int tt = 0; tt < 2; ++tt) {
        if (!act[tt]) continue;
        const int u = (wvf * 2 + tt) * 4 + grp;
        if (u < HID && col < ROWS) hf[col * 64 + u] = hreg[tt];
    }
    __syncthreads();
    if (tid < ROWS * 3) {
        int m = tid / 3, o = tid - m * 3;
        float s = b_fc[o];
        for (int k = 0; k < HID; ++k)
            s += hf[m * 64 + k] * W_fc[o * HID + k];
        out[(size_t)(b0 + m) * 3 + o] = s;
    }
}

extern "C" void kernel_launch(void* const* d_in, const int* in_sizes, int n_in,
                              void* d_out, int out_size, void* d_ws, size_t ws_size,
                              hipStream_t stream) {
    const float* x    = (const float*)d_in[0];
    const float* W_ih = (const float*)d_in[1];
    const float* W_hh = (const float*)d_in[2];
    const float* b_ih = (const float*)d_in[3];
    const float* b_hh = (const float*)d_in[4];
    const float* W_fc = (const float*)d_in[5];
    const float* b_fc = (const float*)d_in[6];
    float* out = (float*)d_out;

    dim3 grid(4096 / ROWS);   // 512 blocks -> 2 per CU (independent chains)
    dim3 block(NTHREADS);     // 8 waves
    lstm_mfma8_kernel<<<grid, block, 0, stream>>>(x, W_ih, W_hh, b_ih, b_hh,
                                                  W_fc, b_fc, out);
}

// Round 13
// 273.134 us; speedup vs baseline: 1.9370x; 1.9370x over previous
//
#include <hip/hip_runtime.h>

// LSTM B=4096, T=512, I=2, H=50, O=3 — MFMA, round 13.
// vs r10 (308us): shrink the lockstep per-t work on all axes.
//  * h stored as PLAIN bf16 (no lo-plane): 2 (not 4) ds_read_b128/wave,
//    4 (not 6) MFMA/tile. x and bias stay EXACT: x-lo in k=52/53 with
//    duplicated W_ih columns; bias via A-side hi/lo at k=54 (B=1.0).
//  * gate scales folded into weights (i,f,o rows x -log2e; g x +2log2e):
//    epilogue exp2(acc) directly, no muls. bf16 pack via v_cvt_pk_bf16_f32.
//  * RS=144 -> read banks (col+grp)%8 evenly spread (was 8-way conflict).
//  * 256 blocks x 8 waves: waves 0..6 own 2 tiles (13 real), wave 7 = x.
// K map: k<50 h(bf16), 50/51 x-hi, 52/53 x-lo, 54 const-1.0 (bias), 55+ 0.
//   A (M) = weight rows, m=col: u=tau*4+(col>>2), gate=col&3 (VGPR frags)
//   B (N) = h, n-col = batch row (2x ds_read_b128)
//   C: col=lane&15=batch, grp=lane>>4=unit-in-tile, reg=GATE
// ONE barrier per t. Double-buffered h planes.

typedef short bf16x8 __attribute__((ext_vector_type(8)));
typedef float f32x4  __attribute__((ext_vector_type(4)));

#define T_STEPS 512
#define HID     50
#define ROWS    16
#define RS      144                        // bytes per m-row (9 granules)
#define HBUF_SZ (ROWS * RS)                // 2304 B
#define HF_OFF  (2 * HBUF_SZ)              // 4608 B
#define ARENA_SZ (HF_OFF + ROWS * 64 * 4)  // 8704 B
#define NTHREADS 512

#define L2E  1.442695040888963f
#define L2E2 2.885390081777927f

// init-time RTN bf16 hi/lo split (packed: lo short = hi(f), hi short = lo resid)
__device__ __forceinline__ unsigned pack_hilo(float f) {
    unsigned u  = __float_as_uint(f);
    unsigned hi = (u + 0x7fffu + ((u >> 16) & 1u)) >> 16;
    float    fh = __uint_as_float(hi << 16);
    float    rl = f - fh;
    unsigned ul = __float_as_uint(rl);
    unsigned lo = (ul + 0x7fffu + ((ul >> 16) & 1u)) >> 16;
    return (hi & 0xFFFFu) | (lo << 16);
}
// 1-instr packed bf16 RNE: low short = bf16(a), high short = bf16(b)
__device__ __forceinline__ unsigned cvt_pk_bf16(float a, float b) {
    unsigned r;
    asm("v_cvt_pk_bf16_f32 %0, %1, %2" : "=v"(r) : "v"(a), "v"(b));
    return r;
}

__global__ __launch_bounds__(NTHREADS) void lstm_mfma9_kernel(
    const float* __restrict__ x,     // [B,T,2]
    const float* __restrict__ W_ih,  // [200,2]
    const float* __restrict__ W_hh,  // [200,50]
    const float* __restrict__ b_ih,  // [200]
    const float* __restrict__ b_hh,  // [200]
    const float* __restrict__ W_fc,  // [3,50]
    const float* __restrict__ b_fc,  // [3]
    float* __restrict__ out)         // [B,3]
{
    __shared__ __align__(16) char arena[ARENA_SZ];

    const int tid  = threadIdx.x;
    const int lane = tid & 63;
    const int wvf  = tid >> 6;         // wave 0..7
    const int col  = lane & 15;        // C col = batch row; A row index m
    const int grp  = lane >> 4;        // k-group; C row-group = unit-in-tile
    const int b0   = blockIdx.x * ROWS;

    // ---- zero arena ----
    for (int i = tid; i < ARENA_SZ / 4; i += NTHREADS) ((int*)arena)[i] = 0;

    // ---- A-frags (scaled weights, hi/lo) for tiles tau = 2*wvf + tt ----
    bf16x8 awhi[2][2], awlo[2][2];   // [tt][kt]
    bool act[2];
#pragma unroll
    for (int tt = 0; tt < 2; ++tt) {
        const int tau = wvf * 2 + tt;
        act[tt] = (wvf < 7) && (tau * 4 < HID);
        const int u = tau * 4 + (col >> 2);
        const int g = col & 3;
        const float s = (g == 2) ? L2E2 : -L2E;   // fold gate scale into W
#pragma unroll
        for (int kt = 0; kt < 2; ++kt) {
            bf16x8 H, L;
#pragma unroll
            for (int e = 0; e < 8; ++e) {
                int k = kt * 32 + grp * 8 + e;
                float v = 0.f;
                if (act[tt] && u < HID) {
                    int j = g * HID + u;
                    if      (k < HID)  v = W_hh[j * HID + k];
                    else if (k == 50 || k == 52)  v = W_ih[2 * j + 0];
                    else if (k == 51 || k == 53)  v = W_ih[2 * j + 1];
                    else if (k == 54)  v = b_ih[j] + b_hh[j];
                }
                unsigned p = pack_hilo(v * s);
                H[e] = (short)(p & 0xFFFFu);
                L[e] = (short)(p >> 16);
            }
            awhi[tt][kt] = H;
            awlo[tt][kt] = L;
        }
    }

    __syncthreads();   // zeroing complete

    // const-1.0 at k=54 (byte 108), both buffers (bias multiplier)
    if (tid < 2 * ROWS) {
        int buf = tid >> 4, m = tid & 15;
        *(short*)(arena + buf * HBUF_SZ + m * RS + 108) = (short)0x3F80;
    }
    // x writer: wave 7, lanes 0..15 (lane = batch row)
    const bool xwriter = (wvf == 7) && (lane < 16);
    const float* xptr = x + (size_t)(b0 + lane) * (T_STEPS * 2);
    if (xwriter) {   // x(t=0) into buffer 0: hi at bytes 100..103, lo 104..107
        float2 xv = *(const float2*)xptr;
        unsigned xh = cvt_pk_bf16(xv.x, xv.y);
        float f0 = __uint_as_float(xh << 16);
        float f1 = __uint_as_float(xh & 0xFFFF0000u);
        unsigned xl = cvt_pk_bf16(xv.x - f0, xv.y - f1);
        *(unsigned*)(arena + lane * RS + 100) = xh;
        *(unsigned*)(arena + lane * RS + 104) = xl;
    }
    float2 xpre = xwriter ? *(const float2*)(xptr + 2) : make_float2(0.f, 0.f);

    float c2[2]   = {0.f, 0.f};
    float hreg[2] = {0.f, 0.f};

    __syncthreads();

    int pb = 0;
    for (int t = 0; t < T_STEPS; ++t) {
        char* db = arena + (pb ^ 1) * HBUF_SZ;

        if (wvf < 7) {
            // ---- B-frags: 2 ds_read_b128 (bf16 h plane), shared by tiles ----
            const char* hb = arena + pb * HBUF_SZ + col * RS + grp * 16;
            bf16x8 bh0 = *(const bf16x8*)(hb);
            bf16x8 bh1 = *(const bf16x8*)(hb + 64);

            // ---- per tile: 4 MFMA in two independent 2-chains ----
            f32x4 acc[2];
#pragma unroll
            for (int tt = 0; tt < 2; ++tt) {
                if (!act[tt]) continue;
                f32x4 a0 = {0.f, 0.f, 0.f, 0.f};
                f32x4 a1 = {0.f, 0.f, 0.f, 0.f};
                a0 = __builtin_amdgcn_mfma_f32_16x16x32_bf16(awhi[tt][0], bh0, a0, 0, 0, 0);
                a1 = __builtin_amdgcn_mfma_f32_16x16x32_bf16(awhi[tt][1], bh1, a1, 0, 0, 0);
                a0 = __builtin_amdgcn_mfma_f32_16x16x32_bf16(awlo[tt][0], bh0, a0, 0, 0, 0);
                a1 = __builtin_amdgcn_mfma_f32_16x16x32_bf16(awlo[tt][1], bh1, a1, 0, 0, 0);
                acc[tt] = a0 + a1;
            }

            // ---- epilogue: scales pre-folded -> exp2 direct ----
#pragma unroll
            for (int tt = 0; tt < 2; ++tt) {
                if (!act[tt]) continue;
                const int u = (wvf * 2 + tt) * 4 + grp;
                float ei = __builtin_amdgcn_exp2f(acc[tt][0]);
                float ef = __builtin_amdgcn_exp2f(acc[tt][1]);
                float eg = __builtin_amdgcn_exp2f(acc[tt][2]);
                float eo = __builtin_amdgcn_exp2f(acc[tt][3]);
                float sf    = __builtin_amdgcn_rcpf(1.0f + ef);
                float ig_tg = (eg - 1.0f) * __builtin_amdgcn_rcpf((1.0f + ei) * (eg + 1.0f));
                float c = sf * c2[tt] + ig_tg;
                c = fminf(fmaxf(c, -32.0f), 32.0f);
                c2[tt] = c;
                float ec = __builtin_amdgcn_exp2f(L2E2 * c);
                float h  = (ec - 1.0f) * __builtin_amdgcn_rcpf((1.0f + eo) * (ec + 1.0f));
                hreg[tt] = h;
                if (u < HID) {
                    unsigned hp = cvt_pk_bf16(h, h);
                    *(short*)(db + col * RS + u * 2) = (short)(hp & 0xFFFFu);
                }
            }
        }

        // ---- x(t+1) into next buffer; prefetch x(t+2) ----
        if (xwriter) {
            unsigned xh = cvt_pk_bf16(xpre.x, xpre.y);
            float f0 = __uint_as_float(xh << 16);
            float f1 = __uint_as_float(xh & 0xFFFF0000u);
            unsigned xl = cvt_pk_bf16(xpre.x - f0, xpre.y - f1);
            *(unsigned*)(db + lane * RS + 100) = xh;
            *(unsigned*)(db + lane * RS + 104) = xl;
            int t2 = (t + 2 < T_STEPS) ? t + 2 : T_STEPS - 1;
            xpre = *(const float2*)(xptr + (size_t)t2 * 2);
        }

        pb ^= 1;
        __syncthreads();
    }

    // ---- final FC from fp32 h regs ----
    float* hf = (float*)(arena + HF_OFF);   // [16][64]
#pragma unroll
    for (int tt = 0; tt < 2; ++tt) {
        if (!act[tt]) continue;
        const int u = (wvf * 2 + tt) * 4 + grp;
        if (u < HID) hf[col * 64 + u] = hreg[tt];
    }
    __syncthreads();
    if (tid < ROWS * 3) {
        int m = tid / 3, o = tid - m * 3;
        float s = b_fc[o];
        for (int k = 0; k < HID; ++k)
            s += hf[m * 64 + k] * W_fc[o * HID + k];
        out[(size_t)(b0 + m) * 3 + o] = s;
    }
}

extern "C" void kernel_launch(void* const* d_in, const int* in_sizes, int n_in,
                              void* d_out, int out_size, void* d_ws, size_t ws_size,
                              hipStream_t stream) {
    const float* x    = (const float*)d_in[0];
    const float* W_ih = (const float*)d_in[1];
    const float* W_hh = (const float*)d_in[2];
    const float* b_ih = (const float*)d_in[3];
    const float* b_hh = (const float*)d_in[4];
    const float* W_fc = (const float*)d_in[5];
    const float* b_fc = (const float*)d_in[6];
    float* out = (float*)d_out;

    dim3 grid(4096 / ROWS);   // 256 blocks -> 1 per CU
    dim3 block(NTHREADS);     // 8 waves
    lstm_mfma9_kernel<<<grid, block, 0, stream>>>(x, W_ih, W_hh, b_ih, b_hh,
                                                  W_fc, b_fc, out);
}